// Round 1
// baseline (2029.012 us; speedup 1.0000x reference)
//
#include <hip/hip_runtime.h>

// ---------- shapes ----------
#define BB 32
#define CIN 128
#define HH 64
#define WW 64
#define EE 384
#define EBC 128   // per-branch channels
#define HID 24
#define NPIX (HH*WW)          // 4096
#define NTOK (BB*NPIX)        // 131072

typedef __attribute__((ext_vector_type(8))) short short8;
typedef __attribute__((ext_vector_type(4))) float f32x4;
typedef __attribute__((ext_vector_type(4))) unsigned short us4;

__device__ __forceinline__ unsigned short f2bf(float f) {
    unsigned u = __float_as_uint(f);
    unsigned r = u + 0x7fffu + ((u >> 16) & 1u);
    return (unsigned short)(r >> 16);
}
__device__ __forceinline__ float bf2f(unsigned short u) {
    return __uint_as_float(((unsigned)u) << 16);
}
// monotone float -> uint mapping for atomicMax over signed floats
__device__ __forceinline__ unsigned fmapu(float f) {
    unsigned u = __float_as_uint(f);
    return (u & 0x80000000u) ? ~u : (u | 0x80000000u);
}
__device__ __forceinline__ float funmap(unsigned u) {
    unsigned b = (u & 0x80000000u) ? (u ^ 0x80000000u) : ~u;
    return __uint_as_float(b);
}

// ---------- P0a: x [B,C,H,W] f32 -> xh [B,H,W,C] bf16 ----------
__global__ void repack_x(const float* __restrict__ x, unsigned short* __restrict__ xh) {
    int y = blockIdx.x, b = blockIdx.y;
    const float* xp = x + (((size_t)b * CIN) * HH + y) * WW;      // + c*4096 + xc
    unsigned short* op = xh + (((size_t)b * HH + y) * WW) * CIN;  // [xc][c]
    for (int i = threadIdx.x; i < WW * CIN; i += 256) {
        int c = i & (CIN - 1), xc = i >> 7;
        op[xc * CIN + c] = f2bf(xp[(size_t)c * (HH * WW) + xc]);
    }
}

// ---------- P0b: conv weights -> [t][O][C] bf16 (t = global dy*k+dx slot),
//            fusion_w -> bf16, init pool buffers ----------
__global__ void repack_w(const float* __restrict__ w3, const float* __restrict__ w5,
                         const float* __restrict__ w7, const float* __restrict__ fw,
                         unsigned short* __restrict__ wrep, unsigned short* __restrict__ fwb,
                         float* __restrict__ psum, unsigned* __restrict__ pmax) {
    int idx = blockIdx.x * 256 + threadIdx.x;
    if (idx < 83 * 16384) {
        int t = idx >> 14;
        int r = idx & 16383;
        int o = r >> 7, c = r & 127;
        float v;
        if (t < 9)       { int tt = t;      int dy = tt / 3, dx = tt % 3; v = w3[((o * CIN + c) * 3 + dy) * 3 + dx]; }
        else if (t < 34) { int tt = t - 9;  int dy = tt / 5, dx = tt % 5; v = w5[((o * CIN + c) * 5 + dy) * 5 + dx]; }
        else             { int tt = t - 34; int dy = tt / 7, dx = tt % 7; v = w7[((o * CIN + c) * 7 + dy) * 7 + dx]; }
        wrep[idx] = f2bf(v);
    }
    if (idx < EE * EE) fwb[idx] = f2bf(fw[idx]);
    if (idx < BB * EE) { psum[idx] = 0.f; pmax[idx] = 0u; }
}

// ---------- P1: conv branch as implicit GEMM (shift decomposition) ----------
// block: one b, 2 rows (128 pixels), M=128 out channels. 4 waves, each 32 pixels x 128 ch.
template <int KS>
__global__ __launch_bounds__(256, 2) void conv_mfma(
        const unsigned short* __restrict__ xh, const unsigned short* __restrict__ wrp,
        const float* __restrict__ bias, unsigned short* __restrict__ fused,
        float* __restrict__ psum, unsigned* __restrict__ pmax, int choff) {
    constexpr int PK = KS / 2;
    int ry = blockIdx.x, b = blockIdx.y;
    int y0 = ry * 2;
    int lane = threadIdx.x & 63, wv = threadIdx.x >> 6;
    int l16 = lane & 15, g4 = lane >> 4;

    f32x4 acc[8][2];
    #pragma unroll
    for (int i = 0; i < 8; ++i)
        #pragma unroll
        for (int j = 0; j < 2; ++j) acc[i][j] = (f32x4){0.f, 0.f, 0.f, 0.f};

    const unsigned short* xb = xh + (size_t)b * (HH * WW * CIN);

    for (int dy = 0; dy < KS; ++dy) {
        for (int dx = 0; dx < KS; ++dx) {
            const unsigned short* wp = wrp + ((dy * KS + dx) * EBC) * CIN;
            for (int cb = 0; cb < 4; ++cb) {
                int c0 = cb * 32 + g4 * 8;
                short8 a[8];
                #pragma unroll
                for (int mt = 0; mt < 8; ++mt)
                    a[mt] = *(const short8*)(wp + (mt * 16 + l16) * CIN + c0);
                #pragma unroll
                for (int t = 0; t < 2; ++t) {
                    int p0t = wv * 32 + t * 16;
                    int rowl = p0t >> 6;
                    int col = (p0t & 63) + l16;
                    int iy = y0 + rowl + dy - PK;
                    int ix = col + dx - PK;
                    short8 bf = {};
                    if ((unsigned)iy < (unsigned)HH && (unsigned)ix < (unsigned)WW)
                        bf = *(const short8*)(xb + ((iy * WW + ix) * CIN + c0));
                    #pragma unroll
                    for (int mt = 0; mt < 8; ++mt)
                        acc[mt][t] = __builtin_amdgcn_mfma_f32_16x16x32_bf16(a[mt], bf, acc[mt][t], 0, 0, 0);
                }
            }
        }
    }

    // epilogue: bias, store bf16 fused (NHWC/token layout), channel pooling
    #pragma unroll
    for (int mt = 0; mt < 8; ++mt) {
        int orow = mt * 16 + g4 * 4;  // C/D: row = g4*4 + reg
        f32x4 bv = *(const f32x4*)(bias + orow);
        float v[2][4];
        #pragma unroll
        for (int t = 0; t < 2; ++t) {
            int p0t = wv * 32 + t * 16;
            int pix = (y0 + (p0t >> 6)) * WW + ((p0t & 63) + l16);  // col = lane&15
            us4 pk;
            #pragma unroll
            for (int r = 0; r < 4; ++r) {
                float vv = acc[mt][t][r] + bv[r];
                v[t][r] = vv;
                pk[r] = f2bf(vv);
            }
            *(us4*)(fused + ((size_t)(b * NPIX + pix)) * EE + choff + orow) = pk;
        }
        #pragma unroll
        for (int r = 0; r < 4; ++r) {
            float s = v[0][r] + v[1][r];
            float m = fmaxf(v[0][r], v[1][r]);
            #pragma unroll
            for (int sh = 1; sh < 16; sh <<= 1) {
                s += __shfl_xor(s, sh);
                m = fmaxf(m, __shfl_xor(m, sh));
            }
            if (l16 == 0) {
                atomicAdd(&psum[b * EE + choff + orow + r], s);
                atomicMax(&pmax[b * EE + choff + orow + r], fmapu(m));
            }
        }
    }
}

// ---------- P2: channel attention (uses W2·relu(a)+W2·relu(b) = W2·(relu(a)+relu(b))) ----------
__global__ void attn_kernel(const float* __restrict__ psum, const unsigned* __restrict__ pmax,
                            const float* __restrict__ ca_w1, const float* __restrict__ ca_w2,
                            float* __restrict__ attn) {
    int b = blockIdx.x;
    __shared__ float av[EE], mxv[EE], hsum[HID];
    int t = threadIdx.x;
    if (t < EE) {
        av[t] = psum[b * EE + t] * (1.0f / (float)NPIX);
        mxv[t] = funmap(pmax[b * EE + t]);
    }
    __syncthreads();
    if (t < HID) {
        float sa = 0.f, sm = 0.f;
        for (int c = 0; c < EE; ++c) {
            float w = ca_w1[t * EE + c];
            sa += w * av[c];
            sm += w * mxv[c];
        }
        hsum[t] = fmaxf(sa, 0.f) + fmaxf(sm, 0.f);
    }
    __syncthreads();
    if (t < EE) {
        float s = 0.f;
        for (int h = 0; h < HID; ++h) s += ca_w2[t * HID + h] * hsum[h];
        attn[b * EE + t] = 1.f / (1.f + __expf(-s));
    }
}

// ---------- P2b: per-batch attn-scaled fusion weights (bf16) ----------
__global__ void scale_fw(const unsigned short* __restrict__ fwb, const float* __restrict__ attn,
                         unsigned short* __restrict__ fws) {
    int b = blockIdx.y;
    int idx = blockIdx.x * 256 + threadIdx.x;
    if (idx < EE * EE) {
        int c = idx % EE;
        fws[(size_t)b * (EE * EE) + idx] = f2bf(bf2f(fwb[idx]) * attn[b * EE + c]);
    }
}

// ---------- P3: 1x1 fusion GEMM + fused LayerNorm ----------
// block: one b, 64 tokens, M=384. 4 waves split M (96 each), all 64 tokens.
__global__ __launch_bounds__(256, 2) void fuse_ln(
        const unsigned short* __restrict__ fused, const unsigned short* __restrict__ fws,
        const float* __restrict__ fusion_b, const float* __restrict__ ln_g,
        const float* __restrict__ ln_b, float* __restrict__ out) {
    int b = blockIdx.y;
    int p0 = blockIdx.x * 64;
    int lane = threadIdx.x & 63, wv = threadIdx.x >> 6;
    int l16 = lane & 15, g4 = lane >> 4;

    f32x4 acc[6][4];
    #pragma unroll
    for (int i = 0; i < 6; ++i)
        #pragma unroll
        for (int j = 0; j < 4; ++j) acc[i][j] = (f32x4){0.f, 0.f, 0.f, 0.f};

    const unsigned short* fb = fused + ((size_t)(b * NPIX + p0)) * EE;
    const unsigned short* wb = fws + (size_t)b * (EE * EE);

    for (int cb = 0; cb < 12; ++cb) {
        int c0 = cb * 32 + g4 * 8;
        short8 a[6];
        #pragma unroll
        for (int mt = 0; mt < 6; ++mt)
            a[mt] = *(const short8*)(wb + (wv * 96 + mt * 16 + l16) * EE + c0);
        #pragma unroll
        for (int nt = 0; nt < 4; ++nt) {
            short8 bf = *(const short8*)(fb + (nt * 16 + l16) * EE + c0);
            #pragma unroll
            for (int mt = 0; mt < 6; ++mt)
                acc[mt][nt] = __builtin_amdgcn_mfma_f32_16x16x32_bf16(a[mt], bf, acc[mt][nt], 0, 0, 0);
        }
    }

    __shared__ float s_sum[4][64], s_sq[4][64], s_mean[64], s_rstd[64];

    // bias add + per-wave LN partials
    #pragma unroll
    for (int nt = 0; nt < 4; ++nt) {
        float ps = 0.f, pq = 0.f;
        #pragma unroll
        for (int mt = 0; mt < 6; ++mt) {
            int o = wv * 96 + mt * 16 + g4 * 4;
            f32x4 bv = *(const f32x4*)(fusion_b + o);
            #pragma unroll
            for (int r = 0; r < 4; ++r) {
                float v = acc[mt][nt][r] + bv[r];
                acc[mt][nt][r] = v;
                ps += v;
                pq += v * v;
            }
        }
        ps += __shfl_xor(ps, 16); pq += __shfl_xor(pq, 16);
        ps += __shfl_xor(ps, 32); pq += __shfl_xor(pq, 32);
        if (g4 == 0) { s_sum[wv][nt * 16 + l16] = ps; s_sq[wv][nt * 16 + l16] = pq; }
    }
    __syncthreads();
    if (threadIdx.x < 64) {
        int pix = threadIdx.x;
        float s = 0.f, q = 0.f;
        #pragma unroll
        for (int w = 0; w < 4; ++w) { s += s_sum[w][pix]; q += s_sq[w][pix]; }
        float mean = s * (1.0f / (float)EE);
        float var = q * (1.0f / (float)EE) - mean * mean;
        s_mean[pix] = mean;
        s_rstd[pix] = rsqrtf(var + 1e-5f);
    }
    __syncthreads();

    #pragma unroll
    for (int nt = 0; nt < 4; ++nt) {
        int pix = nt * 16 + l16;
        float mean = s_mean[pix], rstd = s_rstd[pix];
        size_t tokbase = ((size_t)(b * NPIX + p0 + pix)) * EE;
        #pragma unroll
        for (int mt = 0; mt < 6; ++mt) {
            int o = wv * 96 + mt * 16 + g4 * 4;
            f32x4 g = *(const f32x4*)(ln_g + o);
            f32x4 be = *(const f32x4*)(ln_b + o);
            f32x4 res;
            #pragma unroll
            for (int r = 0; r < 4; ++r)
                res[r] = (acc[mt][nt][r] - mean) * rstd * g[r] + be[r];
            *(f32x4*)(out + tokbase + o) = res;
        }
    }
}

// ---------- launch ----------
extern "C" void kernel_launch(void* const* d_in, const int* in_sizes, int n_in,
                              void* d_out, int out_size, void* d_ws, size_t ws_size,
                              hipStream_t stream) {
    const float* x    = (const float*)d_in[0];
    const float* w3   = (const float*)d_in[1];
    const float* b3   = (const float*)d_in[2];
    const float* w5   = (const float*)d_in[3];
    const float* b5   = (const float*)d_in[4];
    const float* w7   = (const float*)d_in[5];
    const float* b7   = (const float*)d_in[6];
    const float* caw1 = (const float*)d_in[7];
    const float* caw2 = (const float*)d_in[8];
    const float* fw   = (const float*)d_in[9];
    const float* fbias= (const float*)d_in[10];
    const float* lng  = (const float*)d_in[11];
    const float* lnb  = (const float*)d_in[12];
    float* out = (float*)d_out;

    char* ws = (char*)d_ws;
    size_t off = 0;
    unsigned short* xh   = (unsigned short*)(ws + off); off += (size_t)BB * HH * WW * CIN * 2;       // 33.5 MB
    unsigned short* wrep = (unsigned short*)(ws + off); off += (size_t)83 * EBC * CIN * 2;           // 2.7 MB
    unsigned short* fwb  = (unsigned short*)(ws + off); off += (size_t)EE * EE * 2;                  // 0.3 MB
    unsigned short* fws  = (unsigned short*)(ws + off); off += (size_t)BB * EE * EE * 2;             // 9.4 MB
    unsigned short* fused= (unsigned short*)(ws + off); off += (size_t)NTOK * EE * 2;                // 100.7 MB
    float*    psum = (float*)(ws + off);    off += (size_t)BB * EE * 4;
    unsigned* pmax = (unsigned*)(ws + off); off += (size_t)BB * EE * 4;
    float*    attn = (float*)(ws + off);    off += (size_t)BB * EE * 4;

    repack_x<<<dim3(HH, BB), 256, 0, stream>>>(x, xh);
    repack_w<<<dim3(5312), 256, 0, stream>>>(w3, w5, w7, fw, wrep, fwb, psum, pmax);

    conv_mfma<3><<<dim3(32, BB), 256, 0, stream>>>(xh, wrep + 0 * 16384,  b3, fused, psum, pmax, 0);
    conv_mfma<5><<<dim3(32, BB), 256, 0, stream>>>(xh, wrep + 9 * 16384,  b5, fused, psum, pmax, 128);
    conv_mfma<7><<<dim3(32, BB), 256, 0, stream>>>(xh, wrep + 34 * 16384, b7, fused, psum, pmax, 256);

    attn_kernel<<<dim3(BB), 384, 0, stream>>>(psum, pmax, caw1, caw2, attn);
    scale_fw<<<dim3(576, BB), 256, 0, stream>>>(fwb, attn, fws);
    fuse_ln<<<dim3(NPIX / 64, BB), 256, 0, stream>>>(fused, fws, fbias, lng, lnb, out);
}

// Round 2
// 1099.328 us; speedup vs baseline: 1.8457x; 1.8457x over previous
//
#include <hip/hip_runtime.h>

// ---------- shapes ----------
#define BB 32
#define CIN 128
#define HH 64
#define WW 64
#define EE 384
#define EBC 128   // per-branch channels
#define HID 24
#define NPIX (HH*WW)          // 4096
#define NTOK (BB*NPIX)        // 131072

typedef __attribute__((ext_vector_type(8))) short short8;
typedef __attribute__((ext_vector_type(4))) float f32x4;
typedef __attribute__((ext_vector_type(4))) unsigned short us4;

__device__ __forceinline__ unsigned short f2bf(float f) {
    unsigned u = __float_as_uint(f);
    unsigned r = u + 0x7fffu + ((u >> 16) & 1u);
    return (unsigned short)(r >> 16);
}
__device__ __forceinline__ float bf2f(unsigned short u) {
    return __uint_as_float(((unsigned)u) << 16);
}
// monotone float -> uint mapping for atomicMax over signed floats
__device__ __forceinline__ unsigned fmapu(float f) {
    unsigned u = __float_as_uint(f);
    return (u & 0x80000000u) ? ~u : (u | 0x80000000u);
}
__device__ __forceinline__ float funmap(unsigned u) {
    unsigned b = (u & 0x80000000u) ? (u ^ 0x80000000u) : ~u;
    return __uint_as_float(b);
}

// ---------- P0a: x [B,C,H,W] f32 -> xh [B,H,W,C] bf16 ----------
__global__ void repack_x(const float* __restrict__ x, unsigned short* __restrict__ xh) {
    int y = blockIdx.x, b = blockIdx.y;
    const float* xp = x + (((size_t)b * CIN) * HH + y) * WW;      // + c*4096 + xc
    unsigned short* op = xh + (((size_t)b * HH + y) * WW) * CIN;  // [xc][c]
    for (int i = threadIdx.x; i < WW * CIN; i += 256) {
        int c = i & (CIN - 1), xc = i >> 7;
        op[xc * CIN + c] = f2bf(xp[(size_t)c * (HH * WW) + xc]);
    }
}

// ---------- P0b: conv weights -> [t][O][C] bf16, fusion_w -> bf16, init pools ----------
__global__ void repack_w(const float* __restrict__ w3, const float* __restrict__ w5,
                         const float* __restrict__ w7, const float* __restrict__ fw,
                         unsigned short* __restrict__ wrep, unsigned short* __restrict__ fwb,
                         float* __restrict__ psum, unsigned* __restrict__ pmax) {
    int idx = blockIdx.x * 256 + threadIdx.x;
    if (idx < 83 * 16384) {
        int t = idx >> 14;
        int r = idx & 16383;
        int o = r >> 7, c = r & 127;
        float v;
        if (t < 9)       { int tt = t;      int dy = tt / 3, dx = tt % 3; v = w3[((o * CIN + c) * 3 + dy) * 3 + dx]; }
        else if (t < 34) { int tt = t - 9;  int dy = tt / 5, dx = tt % 5; v = w5[((o * CIN + c) * 5 + dy) * 5 + dx]; }
        else             { int tt = t - 34; int dy = tt / 7, dx = tt % 7; v = w7[((o * CIN + c) * 7 + dy) * 7 + dx]; }
        wrep[idx] = f2bf(v);
    }
    if (idx < EE * EE) fwb[idx] = f2bf(fw[idx]);
    if (idx < BB * EE) { psum[idx] = 0.f; pmax[idx] = 0u; }
}

// ---------- P1: conv as implicit GEMM, LDS-staged input tile ----------
// block: one b, 4 output rows. Wave wv handles output row y0+wv, all 64 px, all 128 out-ch.
// K-loop: cb (4 chunks of 32 ch) outer with LDS staging; (dy,dx) inner reusing the tile.
template <int KS>
__global__ __launch_bounds__(256, 2) void conv_mfma(
        const unsigned short* __restrict__ xh, const unsigned short* __restrict__ wrp,
        const float* __restrict__ bias, unsigned short* __restrict__ fused,
        float* __restrict__ psum, unsigned* __restrict__ pmax, int choff) {
    constexpr int PK = KS / 2;
    constexpr int RT = 4 + 2 * PK;    // tile rows
    constexpr int TPX = 64 + 2 * PK;  // tile px (with halo)
    constexpr int NCH = RT * 4 * TPX; // 16B chunks in tile

    __shared__ short8 smem[NCH];

    int b = blockIdx.y;
    int y0 = blockIdx.x * 4;
    int lane = threadIdx.x & 63, wv = threadIdx.x >> 6;
    int l16 = lane & 15, g4 = lane >> 4;

    f32x4 acc[8][4];
    #pragma unroll
    for (int i = 0; i < 8; ++i)
        #pragma unroll
        for (int j = 0; j < 4; ++j) acc[i][j] = (f32x4){0.f, 0.f, 0.f, 0.f};

    const unsigned short* xb = xh + (size_t)b * (HH * WW * CIN);

    for (int cb = 0; cb < 4; ++cb) {
        if (cb) __syncthreads();
        // stage tile: i = ((r*TPX + p)<<2) | g  -> 4 consecutive threads read 64B contiguous global
        for (int i = threadIdx.x; i < NCH; i += 256) {
            int g = i & 3;
            int rp = i >> 2;
            int p = rp % TPX;
            int r = rp / TPX;
            int iy = y0 + r - PK, ix = p - PK;
            short8 v = {};
            if ((unsigned)iy < (unsigned)HH && (unsigned)ix < (unsigned)WW)
                v = *(const short8*)(xb + ((iy * WW + ix) * CIN + cb * 32 + g * 8));
            smem[(r * 4 + g) * TPX + p] = v;
        }
        __syncthreads();

        const unsigned short* wbase = wrp + l16 * CIN + cb * 32 + g4 * 8;
        #pragma unroll 1
        for (int dy = 0; dy < KS; ++dy) {
            int lrow = ((wv + dy) * 4 + g4) * TPX + l16;
            #pragma unroll
            for (int dx = 0; dx < KS; ++dx) {
                const unsigned short* wp = wbase + (size_t)(dy * KS + dx) * (EBC * CIN);
                short8 a[8];
                #pragma unroll
                for (int mt = 0; mt < 8; ++mt)
                    a[mt] = *(const short8*)(wp + mt * 16 * CIN);
                #pragma unroll
                for (int nt = 0; nt < 4; ++nt) {
                    short8 bf = smem[lrow + dx + nt * 16];
                    #pragma unroll
                    for (int mt = 0; mt < 8; ++mt)
                        acc[mt][nt] = __builtin_amdgcn_mfma_f32_16x16x32_bf16(a[mt], bf, acc[mt][nt], 0, 0, 0);
                }
            }
        }
    }

    // epilogue: bias, bf16 store (token layout), channel pooling
    int y = y0 + wv;
    #pragma unroll
    for (int mt = 0; mt < 8; ++mt) {
        int orow = mt * 16 + g4 * 4;  // C/D: row = g4*4 + reg
        f32x4 bv = *(const f32x4*)(bias + orow);
        float sacc[4] = {0.f, 0.f, 0.f, 0.f};
        float macc[4] = {-1e30f, -1e30f, -1e30f, -1e30f};
        #pragma unroll
        for (int nt = 0; nt < 4; ++nt) {
            int pix = y * WW + nt * 16 + l16;  // col = lane&15
            us4 pk;
            #pragma unroll
            for (int r = 0; r < 4; ++r) {
                float vv = acc[mt][nt][r] + bv[r];
                sacc[r] += vv;
                macc[r] = fmaxf(macc[r], vv);
                pk[r] = f2bf(vv);
            }
            *(us4*)(fused + ((size_t)(b * NPIX + pix)) * EE + choff + orow) = pk;
        }
        #pragma unroll
        for (int r = 0; r < 4; ++r) {
            float s = sacc[r], m = macc[r];
            #pragma unroll
            for (int sh = 1; sh < 16; sh <<= 1) {
                s += __shfl_xor(s, sh);
                m = fmaxf(m, __shfl_xor(m, sh));
            }
            if (l16 == 0) {
                atomicAdd(&psum[b * EE + choff + orow + r], s);
                atomicMax(&pmax[b * EE + choff + orow + r], fmapu(m));
            }
        }
    }
}

// ---------- P2: channel attention (W2·relu(a)+W2·relu(b) = W2·(relu(a)+relu(b))) ----------
__global__ void attn_kernel(const float* __restrict__ psum, const unsigned* __restrict__ pmax,
                            const float* __restrict__ ca_w1, const float* __restrict__ ca_w2,
                            float* __restrict__ attn) {
    int b = blockIdx.x;
    __shared__ float av[EE], mxv[EE], hsum[HID];
    int t = threadIdx.x;
    if (t < EE) {
        av[t] = psum[b * EE + t] * (1.0f / (float)NPIX);
        mxv[t] = funmap(pmax[b * EE + t]);
    }
    __syncthreads();
    if (t < HID) {
        float sa = 0.f, sm = 0.f;
        for (int c = 0; c < EE; ++c) {
            float w = ca_w1[t * EE + c];
            sa += w * av[c];
            sm += w * mxv[c];
        }
        hsum[t] = fmaxf(sa, 0.f) + fmaxf(sm, 0.f);
    }
    __syncthreads();
    if (t < EE) {
        float s = 0.f;
        for (int h = 0; h < HID; ++h) s += ca_w2[t * HID + h] * hsum[h];
        attn[b * EE + t] = 1.f / (1.f + __expf(-s));
    }
}

// ---------- P3: 1x1 fusion GEMM (attn folded into LDS-staged B) + fused LayerNorm ----------
// block: one b, 64 tokens, M=384. 4 waves split M (96 each), all 64 tokens.
#define BPITCH 392  // token pitch in LDS (chs), pad 384->392 to break bank alignment
__global__ __launch_bounds__(256, 2) void fuse_ln(
        const unsigned short* __restrict__ fused, const unsigned short* __restrict__ fwb,
        const float* __restrict__ attn,
        const float* __restrict__ fusion_b, const float* __restrict__ ln_g,
        const float* __restrict__ ln_b, float* __restrict__ out) {
    int b = blockIdx.y;
    int p0 = blockIdx.x * 64;
    int lane = threadIdx.x & 63, wv = threadIdx.x >> 6;
    int l16 = lane & 15, g4 = lane >> 4;

    __shared__ unsigned short sB[64 * BPITCH];
    __shared__ float sattn[EE];
    __shared__ float s_sum[4][64], s_sq[4][64], s_mean[64], s_rstd[64];

    for (int i = threadIdx.x; i < EE; i += 256) sattn[i] = attn[b * EE + i];
    __syncthreads();

    // stage 64 tokens x 384 ch, scaled by attn
    const unsigned short* fb = fused + ((size_t)(b * NPIX + p0)) * EE;
    for (int i = threadIdx.x; i < 64 * 48; i += 256) {
        int cg = i % 48, tok = i / 48;
        short8 raw = *(const short8*)(fb + tok * EE + cg * 8);
        short8 o;
        #pragma unroll
        for (int j = 0; j < 8; ++j)
            o[j] = (short)f2bf(bf2f((unsigned short)raw[j]) * sattn[cg * 8 + j]);
        *(short8*)(sB + tok * BPITCH + cg * 8) = o;
    }
    __syncthreads();

    f32x4 acc[6][4];
    #pragma unroll
    for (int i = 0; i < 6; ++i)
        #pragma unroll
        for (int j = 0; j < 4; ++j) acc[i][j] = (f32x4){0.f, 0.f, 0.f, 0.f};

    for (int cb = 0; cb < 12; ++cb) {
        int c0 = cb * 32 + g4 * 8;
        short8 a[6];
        #pragma unroll
        for (int mt = 0; mt < 6; ++mt)
            a[mt] = *(const short8*)(fwb + (wv * 96 + mt * 16 + l16) * EE + c0);
        #pragma unroll
        for (int nt = 0; nt < 4; ++nt) {
            short8 bf = *(const short8*)(sB + (nt * 16 + l16) * BPITCH + c0);
            #pragma unroll
            for (int mt = 0; mt < 6; ++mt)
                acc[mt][nt] = __builtin_amdgcn_mfma_f32_16x16x32_bf16(a[mt], bf, acc[mt][nt], 0, 0, 0);
        }
    }

    // bias add + per-wave LN partials
    #pragma unroll
    for (int nt = 0; nt < 4; ++nt) {
        float ps = 0.f, pq = 0.f;
        #pragma unroll
        for (int mt = 0; mt < 6; ++mt) {
            int o = wv * 96 + mt * 16 + g4 * 4;
            f32x4 bv = *(const f32x4*)(fusion_b + o);
            #pragma unroll
            for (int r = 0; r < 4; ++r) {
                float v = acc[mt][nt][r] + bv[r];
                acc[mt][nt][r] = v;
                ps += v;
                pq += v * v;
            }
        }
        ps += __shfl_xor(ps, 16); pq += __shfl_xor(pq, 16);
        ps += __shfl_xor(ps, 32); pq += __shfl_xor(pq, 32);
        if (g4 == 0) { s_sum[wv][nt * 16 + l16] = ps; s_sq[wv][nt * 16 + l16] = pq; }
    }
    __syncthreads();
    if (threadIdx.x < 64) {
        int pix = threadIdx.x;
        float s = 0.f, q = 0.f;
        #pragma unroll
        for (int w = 0; w < 4; ++w) { s += s_sum[w][pix]; q += s_sq[w][pix]; }
        float mean = s * (1.0f / (float)EE);
        float var = q * (1.0f / (float)EE) - mean * mean;
        s_mean[pix] = mean;
        s_rstd[pix] = rsqrtf(var + 1e-5f);
    }
    __syncthreads();

    #pragma unroll
    for (int nt = 0; nt < 4; ++nt) {
        int pix = nt * 16 + l16;
        float mean = s_mean[pix], rstd = s_rstd[pix];
        size_t tokbase = ((size_t)(b * NPIX + p0 + pix)) * EE;
        #pragma unroll
        for (int mt = 0; mt < 6; ++mt) {
            int o = wv * 96 + mt * 16 + g4 * 4;
            f32x4 g = *(const f32x4*)(ln_g + o);
            f32x4 be = *(const f32x4*)(ln_b + o);
            f32x4 res;
            #pragma unroll
            for (int r = 0; r < 4; ++r)
                res[r] = (acc[mt][nt][r] - mean) * rstd * g[r] + be[r];
            *(f32x4*)(out + tokbase + o) = res;
        }
    }
}

// ---------- launch ----------
extern "C" void kernel_launch(void* const* d_in, const int* in_sizes, int n_in,
                              void* d_out, int out_size, void* d_ws, size_t ws_size,
                              hipStream_t stream) {
    const float* x    = (const float*)d_in[0];
    const float* w3   = (const float*)d_in[1];
    const float* b3   = (const float*)d_in[2];
    const float* w5   = (const float*)d_in[3];
    const float* b5   = (const float*)d_in[4];
    const float* w7   = (const float*)d_in[5];
    const float* b7   = (const float*)d_in[6];
    const float* caw1 = (const float*)d_in[7];
    const float* caw2 = (const float*)d_in[8];
    const float* fw   = (const float*)d_in[9];
    const float* fbias= (const float*)d_in[10];
    const float* lng  = (const float*)d_in[11];
    const float* lnb  = (const float*)d_in[12];
    float* out = (float*)d_out;

    char* ws = (char*)d_ws;
    size_t off = 0;
    unsigned short* xh   = (unsigned short*)(ws + off); off += (size_t)BB * HH * WW * CIN * 2;       // 33.5 MB
    unsigned short* wrep = (unsigned short*)(ws + off); off += (size_t)83 * EBC * CIN * 2;           // 2.7 MB
    unsigned short* fwb  = (unsigned short*)(ws + off); off += (size_t)EE * EE * 2;                  // 0.3 MB
    unsigned short* fused= (unsigned short*)(ws + off); off += (size_t)NTOK * EE * 2;                // 100.7 MB
    float*    psum = (float*)(ws + off);    off += (size_t)BB * EE * 4;
    unsigned* pmax = (unsigned*)(ws + off); off += (size_t)BB * EE * 4;
    float*    attn = (float*)(ws + off);    off += (size_t)BB * EE * 4;

    repack_x<<<dim3(HH, BB), 256, 0, stream>>>(x, xh);
    repack_w<<<dim3(5312), 256, 0, stream>>>(w3, w5, w7, fw, wrep, fwb, psum, pmax);

    conv_mfma<3><<<dim3(16, BB), 256, 0, stream>>>(xh, wrep + 0 * 16384,  b3, fused, psum, pmax, 0);
    conv_mfma<5><<<dim3(16, BB), 256, 0, stream>>>(xh, wrep + 9 * 16384,  b5, fused, psum, pmax, 128);
    conv_mfma<7><<<dim3(16, BB), 256, 0, stream>>>(xh, wrep + 34 * 16384, b7, fused, psum, pmax, 256);

    attn_kernel<<<dim3(BB), 384, 0, stream>>>(psum, pmax, caw1, caw2, attn);
    fuse_ln<<<dim3(NPIX / 64, BB), 256, 0, stream>>>(fused, fwb, attn, fbias, lng, lnb, out);
}

// Round 3
// 700.764 us; speedup vs baseline: 2.8954x; 1.5688x over previous
//
#include <hip/hip_runtime.h>

// ---------- shapes ----------
#define BB 32
#define CIN 128
#define HH 64
#define WW 64
#define EE 384
#define EBC 128   // per-branch channels
#define HID 24
#define NPIX (HH*WW)          // 4096
#define NTOK (BB*NPIX)        // 131072

typedef __attribute__((ext_vector_type(8))) short short8;
typedef __attribute__((ext_vector_type(4))) float f32x4;
typedef __attribute__((ext_vector_type(4))) unsigned short us4;

__device__ __forceinline__ unsigned short f2bf(float f) {
    unsigned u = __float_as_uint(f);
    unsigned r = u + 0x7fffu + ((u >> 16) & 1u);
    return (unsigned short)(r >> 16);
}
__device__ __forceinline__ float bf2f(unsigned short u) {
    return __uint_as_float(((unsigned)u) << 16);
}
// monotone float -> uint mapping for atomicMax over signed floats
__device__ __forceinline__ unsigned fmapu(float f) {
    unsigned u = __float_as_uint(f);
    return (u & 0x80000000u) ? ~u : (u | 0x80000000u);
}
__device__ __forceinline__ float funmap(unsigned u) {
    unsigned b = (u & 0x80000000u) ? (u ^ 0x80000000u) : ~u;
    return __uint_as_float(b);
}

// ---------- P0a: x [B,C,H,W] f32 -> xh [B,H,W,C] bf16 (LDS transpose, coalesced) ----------
__global__ void repack_x(const float* __restrict__ x, unsigned short* __restrict__ xh) {
    int y = blockIdx.x, b = blockIdx.y;
    __shared__ unsigned short t[CIN][WW + 6];
    const float* xp = x + (((size_t)b * CIN) * HH + y) * WW;
    #pragma unroll
    for (int it = 0; it < 32; ++it) {
        int xc = threadIdx.x & 63;
        int c = (threadIdx.x >> 6) + it * 4;
        t[c][xc] = f2bf(xp[(size_t)c * NPIX + xc]);
    }
    __syncthreads();
    unsigned short* op = xh + (((size_t)b * HH + y) * WW) * CIN;
    #pragma unroll
    for (int it = 0; it < 8; ++it) {
        int id = threadIdx.x + it * 256;
        int xc = id >> 5, c0 = (id & 31) * 4;
        us4 v = { t[c0][xc], t[c0 + 1][xc], t[c0 + 2][xc], t[c0 + 3][xc] };
        *(us4*)(op + xc * CIN + c0) = v;
    }
}

// ---------- P0b: conv weights -> fragment-ordered bf16 [tap][cb][mt][lane][8ch],
//            fusion_w -> fragment-ordered bf16 [cb12][m24][lane][8ch], init pools ----------
__global__ void repack_w(const float* __restrict__ w3, const float* __restrict__ w5,
                         const float* __restrict__ w7, const float* __restrict__ fw,
                         unsigned short* __restrict__ wrep, unsigned short* __restrict__ fwb,
                         float* __restrict__ psum, unsigned* __restrict__ pmax) {
    int idx = blockIdx.x * 256 + threadIdx.x;
    if (idx < 83 * 16384) {
        int j = idx & 7;
        int lane = (idx >> 3) & 63;
        int mt = (idx >> 9) & 7;
        int cb = (idx >> 12) & 3;
        int t = idx >> 14;
        int l16 = lane & 15, g4 = lane >> 4;
        int o = mt * 16 + l16;
        int c = cb * 32 + g4 * 8 + j;
        float v;
        if (t < 9)       { int tt = t;      int dy = tt / 3, dx = tt % 3; v = w3[((o * CIN + c) * 3 + dy) * 3 + dx]; }
        else if (t < 34) { int tt = t - 9;  int dy = tt / 5, dx = tt % 5; v = w5[((o * CIN + c) * 5 + dy) * 5 + dx]; }
        else             { int tt = t - 34; int dy = tt / 7, dx = tt % 7; v = w7[((o * CIN + c) * 7 + dy) * 7 + dx]; }
        wrep[idx] = f2bf(v);
    }
    if (idx < EE * EE) {
        int j = idx & 7;
        int lane = (idx >> 3) & 63;
        int mc = idx >> 9;           // 0..287 = cb*24 + m
        int m = mc % 24, cb = mc / 24;
        int l16 = lane & 15, g4 = lane >> 4;
        int o = m * 16 + l16;
        int c = cb * 32 + g4 * 8 + j;
        fwb[idx] = f2bf(fw[o * EE + c]);
    }
    if (idx < BB * EE) { psum[idx] = 0.f; pmax[idx] = 0u; }
}

// ---------- P1: conv as implicit GEMM, LDS-staged input tile ----------
// block: (y-tile of 4 rows, channel-half of 64, batch). 4 waves, wave = 1 row x 64 px x 64 ch.
template <int KS>
__global__ __launch_bounds__(256, (KS == 7 ? 3 : 4)) void conv_mfma(
        const unsigned short* __restrict__ xh, const unsigned short* __restrict__ wrp,
        const float* __restrict__ bias, unsigned short* __restrict__ fused,
        float* __restrict__ psum, unsigned* __restrict__ pmax, int choff) {
    constexpr int PK = KS / 2;
    constexpr int RT = 4 + 2 * PK;    // tile rows
    constexpr int TPX = 64 + 2 * PK;  // tile px (with halo)
    constexpr int NCH = RT * 4 * TPX; // 16B chunks in tile

    __shared__ short8 smem[NCH];

    int b = blockIdx.z;
    int half = blockIdx.y;
    int y0 = blockIdx.x * 4;
    int lane = threadIdx.x & 63, wv = threadIdx.x >> 6;
    int l16 = lane & 15, g4 = lane >> 4;

    f32x4 acc[4][4];
    #pragma unroll
    for (int i = 0; i < 4; ++i)
        #pragma unroll
        for (int j = 0; j < 4; ++j) acc[i][j] = (f32x4){0.f, 0.f, 0.f, 0.f};

    const unsigned short* xb = xh + (size_t)b * (HH * WW * CIN);
    const short8* wv8 = (const short8*)wrp;

    for (int cb = 0; cb < 4; ++cb) {
        if (cb) __syncthreads();
        for (int i = threadIdx.x; i < NCH; i += 256) {
            int g = i & 3;
            int rp = i >> 2;
            int p = rp % TPX;
            int r = rp / TPX;
            int iy = y0 + r - PK, ix = p - PK;
            short8 v = {};
            if ((unsigned)iy < (unsigned)HH && (unsigned)ix < (unsigned)WW)
                v = *(const short8*)(xb + ((iy * WW + ix) * CIN + cb * 32 + g * 8));
            smem[(r * 4 + g) * TPX + p] = v;
        }
        __syncthreads();

        #pragma unroll 1
        for (int dy = 0; dy < KS; ++dy) {
            int lrow = ((wv + dy) * 4 + g4) * TPX + l16;
            #pragma unroll
            for (int dx = 0; dx < KS; ++dx) {
                // fragment-ordered A: lane-contiguous 1KB per instruction
                const short8* wf = wv8 + (((size_t)(((dy * KS + dx) * 4 + cb) * 8) + half * 4) * 64 + lane);
                short8 a[4];
                #pragma unroll
                for (int mt = 0; mt < 4; ++mt)
                    a[mt] = wf[mt * 64];
                #pragma unroll
                for (int nt = 0; nt < 4; ++nt) {
                    short8 bf = smem[lrow + dx + nt * 16];
                    #pragma unroll
                    for (int mt = 0; mt < 4; ++mt)
                        acc[mt][nt] = __builtin_amdgcn_mfma_f32_16x16x32_bf16(a[mt], bf, acc[mt][nt], 0, 0, 0);
                }
            }
        }
    }

    // epilogue: bias, bf16 store (token layout), channel pooling
    int y = y0 + wv;
    #pragma unroll
    for (int mt = 0; mt < 4; ++mt) {
        int orow = half * 64 + mt * 16 + g4 * 4;  // C/D: row = g4*4 + reg
        f32x4 bv = *(const f32x4*)(bias + orow);
        float sacc[4] = {0.f, 0.f, 0.f, 0.f};
        float macc[4] = {-1e30f, -1e30f, -1e30f, -1e30f};
        #pragma unroll
        for (int nt = 0; nt < 4; ++nt) {
            int pix = y * WW + nt * 16 + l16;  // col = lane&15
            us4 pk;
            #pragma unroll
            for (int r = 0; r < 4; ++r) {
                float vv = acc[mt][nt][r] + bv[r];
                sacc[r] += vv;
                macc[r] = fmaxf(macc[r], vv);
                pk[r] = f2bf(vv);
            }
            *(us4*)(fused + ((size_t)(b * NPIX + pix)) * EE + choff + orow) = pk;
        }
        #pragma unroll
        for (int r = 0; r < 4; ++r) {
            float s = sacc[r], m = macc[r];
            #pragma unroll
            for (int sh = 1; sh < 16; sh <<= 1) {
                s += __shfl_xor(s, sh);
                m = fmaxf(m, __shfl_xor(m, sh));
            }
            if (l16 == 0) {
                atomicAdd(&psum[b * EE + choff + orow + r], s);
                atomicMax(&pmax[b * EE + choff + orow + r], fmapu(m));
            }
        }
    }
}

// ---------- P2: channel attention (W2·relu(a)+W2·relu(b) = W2·(relu(a)+relu(b))) ----------
__global__ void attn_kernel(const float* __restrict__ psum, const unsigned* __restrict__ pmax,
                            const float* __restrict__ ca_w1, const float* __restrict__ ca_w2,
                            float* __restrict__ attn) {
    int b = blockIdx.x;
    __shared__ float av[EE], mxv[EE], hsum[HID];
    int t = threadIdx.x;
    if (t < EE) {
        av[t] = psum[b * EE + t] * (1.0f / (float)NPIX);
        mxv[t] = funmap(pmax[b * EE + t]);
    }
    __syncthreads();
    if (t < HID) {
        float sa = 0.f, sm = 0.f;
        for (int c = 0; c < EE; ++c) {
            float w = ca_w1[t * EE + c];
            sa += w * av[c];
            sm += w * mxv[c];
        }
        hsum[t] = fmaxf(sa, 0.f) + fmaxf(sm, 0.f);
    }
    __syncthreads();
    if (t < EE) {
        float s = 0.f;
        for (int h = 0; h < HID; ++h) s += ca_w2[t * HID + h] * hsum[h];
        attn[b * EE + t] = 1.f / (1.f + __expf(-s));
    }
}

// ---------- P3: 1x1 fusion GEMM (attn folded into LDS-staged B) + fused LayerNorm ----------
// block: one b, 64 tokens, M=384. 4 waves split M (96 each), all 64 tokens.
#define BPITCH 392  // token pitch in LDS (chs)
__global__ __launch_bounds__(256, 2) void fuse_ln(
        const unsigned short* __restrict__ fused, const unsigned short* __restrict__ fwb,
        const float* __restrict__ attn,
        const float* __restrict__ fusion_b, const float* __restrict__ ln_g,
        const float* __restrict__ ln_b, float* __restrict__ out) {
    int b = blockIdx.y;
    int p0 = blockIdx.x * 64;
    int lane = threadIdx.x & 63, wv = threadIdx.x >> 6;
    int l16 = lane & 15, g4 = lane >> 4;

    __shared__ unsigned short sB[64 * BPITCH];
    __shared__ float sattn[EE];
    __shared__ float s_sum[4][64], s_sq[4][64], s_mean[64], s_rstd[64];

    for (int i = threadIdx.x; i < EE; i += 256) sattn[i] = attn[b * EE + i];
    __syncthreads();

    // stage 64 tokens x 384 ch, scaled by attn
    const unsigned short* fb = fused + ((size_t)(b * NPIX + p0)) * EE;
    for (int i = threadIdx.x; i < 64 * 48; i += 256) {
        int cg = i % 48, tok = i / 48;
        short8 raw = *(const short8*)(fb + tok * EE + cg * 8);
        short8 o;
        #pragma unroll
        for (int j = 0; j < 8; ++j)
            o[j] = (short)f2bf(bf2f((unsigned short)raw[j]) * sattn[cg * 8 + j]);
        *(short8*)(sB + tok * BPITCH + cg * 8) = o;
    }
    __syncthreads();

    f32x4 acc[6][4];
    #pragma unroll
    for (int i = 0; i < 6; ++i)
        #pragma unroll
        for (int j = 0; j < 4; ++j) acc[i][j] = (f32x4){0.f, 0.f, 0.f, 0.f};

    const short8* fw8 = (const short8*)fwb;
    for (int cb = 0; cb < 12; ++cb) {
        int c0 = cb * 32 + g4 * 8;
        short8 a[6];
        #pragma unroll
        for (int mt = 0; mt < 6; ++mt)
            a[mt] = fw8[(cb * 24 + wv * 6 + mt) * 64 + lane];  // lane-contiguous
        #pragma unroll
        for (int nt = 0; nt < 4; ++nt) {
            short8 bf = *(const short8*)(sB + (nt * 16 + l16) * BPITCH + c0);
            #pragma unroll
            for (int mt = 0; mt < 6; ++mt)
                acc[mt][nt] = __builtin_amdgcn_mfma_f32_16x16x32_bf16(a[mt], bf, acc[mt][nt], 0, 0, 0);
        }
    }

    // bias add + per-wave LN partials
    #pragma unroll
    for (int nt = 0; nt < 4; ++nt) {
        float ps = 0.f, pq = 0.f;
        #pragma unroll
        for (int mt = 0; mt < 6; ++mt) {
            int o = wv * 96 + mt * 16 + g4 * 4;
            f32x4 bv = *(const f32x4*)(fusion_b + o);
            #pragma unroll
            for (int r = 0; r < 4; ++r) {
                float v = acc[mt][nt][r] + bv[r];
                acc[mt][nt][r] = v;
                ps += v;
                pq += v * v;
            }
        }
        ps += __shfl_xor(ps, 16); pq += __shfl_xor(pq, 16);
        ps += __shfl_xor(ps, 32); pq += __shfl_xor(pq, 32);
        if (g4 == 0) { s_sum[wv][nt * 16 + l16] = ps; s_sq[wv][nt * 16 + l16] = pq; }
    }
    __syncthreads();
    if (threadIdx.x < 64) {
        int pix = threadIdx.x;
        float s = 0.f, q = 0.f;
        #pragma unroll
        for (int w = 0; w < 4; ++w) { s += s_sum[w][pix]; q += s_sq[w][pix]; }
        float mean = s * (1.0f / (float)EE);
        float var = q * (1.0f / (float)EE) - mean * mean;
        s_mean[pix] = mean;
        s_rstd[pix] = rsqrtf(var + 1e-5f);
    }
    __syncthreads();

    #pragma unroll
    for (int nt = 0; nt < 4; ++nt) {
        int pix = nt * 16 + l16;
        float mean = s_mean[pix], rstd = s_rstd[pix];
        size_t tokbase = ((size_t)(b * NPIX + p0 + pix)) * EE;
        #pragma unroll
        for (int mt = 0; mt < 6; ++mt) {
            int o = wv * 96 + mt * 16 + g4 * 4;
            f32x4 g = *(const f32x4*)(ln_g + o);
            f32x4 be = *(const f32x4*)(ln_b + o);
            f32x4 res;
            #pragma unroll
            for (int r = 0; r < 4; ++r)
                res[r] = (acc[mt][nt][r] - mean) * rstd * g[r] + be[r];
            *(f32x4*)(out + tokbase + o) = res;
        }
    }
}

// ---------- launch ----------
extern "C" void kernel_launch(void* const* d_in, const int* in_sizes, int n_in,
                              void* d_out, int out_size, void* d_ws, size_t ws_size,
                              hipStream_t stream) {
    const float* x    = (const float*)d_in[0];
    const float* w3   = (const float*)d_in[1];
    const float* b3   = (const float*)d_in[2];
    const float* w5   = (const float*)d_in[3];
    const float* b5   = (const float*)d_in[4];
    const float* w7   = (const float*)d_in[5];
    const float* b7   = (const float*)d_in[6];
    const float* caw1 = (const float*)d_in[7];
    const float* caw2 = (const float*)d_in[8];
    const float* fw   = (const float*)d_in[9];
    const float* fbias= (const float*)d_in[10];
    const float* lng  = (const float*)d_in[11];
    const float* lnb  = (const float*)d_in[12];
    float* out = (float*)d_out;

    char* ws = (char*)d_ws;
    size_t off = 0;
    unsigned short* xh   = (unsigned short*)(ws + off); off += (size_t)BB * HH * WW * CIN * 2;       // 33.5 MB
    unsigned short* wrep = (unsigned short*)(ws + off); off += (size_t)83 * EBC * CIN * 2;           // 2.7 MB
    unsigned short* fwb  = (unsigned short*)(ws + off); off += (size_t)EE * EE * 2;                  // 0.3 MB
    unsigned short* fused= (unsigned short*)(ws + off); off += (size_t)NTOK * EE * 2;                // 100.7 MB
    float*    psum = (float*)(ws + off);    off += (size_t)BB * EE * 4;
    unsigned* pmax = (unsigned*)(ws + off); off += (size_t)BB * EE * 4;
    float*    attn = (float*)(ws + off);    off += (size_t)BB * EE * 4;

    repack_x<<<dim3(HH, BB), 256, 0, stream>>>(x, xh);
    repack_w<<<dim3(5312), 256, 0, stream>>>(w3, w5, w7, fw, wrep, fwb, psum, pmax);

    conv_mfma<3><<<dim3(16, 2, BB), 256, 0, stream>>>(xh, wrep + 0 * 16384,  b3, fused, psum, pmax, 0);
    conv_mfma<5><<<dim3(16, 2, BB), 256, 0, stream>>>(xh, wrep + 9 * 16384,  b5, fused, psum, pmax, 128);
    conv_mfma<7><<<dim3(16, 2, BB), 256, 0, stream>>>(xh, wrep + 34 * 16384, b7, fused, psum, pmax, 256);

    attn_kernel<<<dim3(BB), 384, 0, stream>>>(psum, pmax, caw1, caw2, attn);
    fuse_ln<<<dim3(NPIX / 64, BB), 256, 0, stream>>>(fused, fwb, attn, fbias, lng, lnb, out);
}